// Round 2
// baseline (1448.865 us; speedup 1.0000x reference)
//
#include <hip/hip_runtime.h>

#define N_NODES 4096
#define C_CH    128
#define NSPEC   10
#define NCUB    165
#define NQUAD   45
#define NMONO   219   // 165 cubic + 45 quad + 9 linear

// ---- workspace layout (bytes) ----
// cnt[10] ints at +0, off[10] ints at +64 (int index 16)
#define WS_CNTOFF 0
#define WS_GLIST  256                       // 4096 ints = 16384
#define WS_U3SYM  16640                     // 4og*165*4k floats = 10560
#define WS_U2SYM  27200                     // 4og*45*2k  floats = 1440
#define WS_COEFF  28672                     // 1280*876 floats = 4485120
#define WS_XG     4513792                   // 1152*4096 floats = 18874368
#define WS_FG     23388160                  // 512*4096 floats  = 8388608
// total ~31.8 MB

// ---------------------------------------------------------------------------
// Kernel 1: permutation-symmetrized U3/U2 (tiny, spread over 8 blocks).
// ---------------------------------------------------------------------------
__global__ void k_prep(const float* __restrict__ U3_0e, const float* __restrict__ U3_1o,
                       const float* __restrict__ U2_0e, const float* __restrict__ U2_1o,
                       float* __restrict__ U3sym, float* __restrict__ U2sym) {
    int task = blockIdx.x * 384 + threadIdx.x;
    if (task >= 2640 + 360) return;
    if (task < 2640) {               // cubic: og(4) * m(165) * k(4)
        int og = task / 660;
        int r  = task - og * 660;
        int m  = r >> 2, k = r & 3;
        int a = 0, b = 0, d = 0;
        {   int idx = 0;
            for (int a0 = 0; a0 < 9; a0++)
                for (int b0 = a0; b0 < 9; b0++)
                    for (int d0 = b0; d0 < 9; d0++) {
                        if (idx == m) { a = a0; b = b0; d = d0; }
                        idx++;
                    }
        }
        const float* U3 = (og == 0) ? U3_0e : U3_1o;
        int o = (og == 0) ? 0 : og - 1;
        const float* Ub = U3 + (size_t)o * 2916;   // [p][q][i][k] strides 324/36/4/1
        #define U3AT(p,q,i) Ub[((p)*9+(q))*36 + (i)*4 + k]
        float sum = U3AT(a,b,d) + U3AT(a,d,b) + U3AT(b,a,d)
                  + U3AT(b,d,a) + U3AT(d,a,b) + U3AT(d,b,a);
        #undef U3AT
        float sc = (a == b && b == d) ? (1.f/6.f)
                 : ((a == b || b == d || a == d) ? 0.5f : 1.f);
        U3sym[(og * 165 + m) * 4 + k] = sum * sc;
    } else {                          // quad: og(4) * q(45) * k(2)
        int t2 = task - 2640;
        int og = t2 / 90;
        int r  = t2 - og * 90;
        int q  = r >> 1, k = r & 1;
        int a = 0, b = 0;
        {   int idx = 0;
            for (int a0 = 0; a0 < 9; a0++)
                for (int b0 = a0; b0 < 9; b0++) { if (idx == q) { a = a0; b = b0; } idx++; }
        }
        const float* U2 = (og == 0) ? U2_0e : U2_1o;
        int o = (og == 0) ? 0 : og - 1;
        const float* Ub = U2 + (size_t)o * 162;    // [p][i][k] strides 18/2/1
        float sum = Ub[(a*9 + b)*2 + k] + Ub[(b*9 + a)*2 + k];
        if (a == b) sum *= 0.5f;
        U2sym[(og * 45 + q) * 2 + k] = sum;
    }
}

// ---------------------------------------------------------------------------
// Kernel 2: single-block species sort: counts, prefix offsets, sorted list.
// ---------------------------------------------------------------------------
__global__ __launch_bounds__(512) void k_sort(const int* __restrict__ specie,
        int* __restrict__ cntoff, int* __restrict__ glist) {
    __shared__ int lcnt[NSPEC], lcur[NSPEC];
    int t = threadIdx.x;
    if (t < NSPEC) lcnt[t] = 0;
    __syncthreads();
    int ss[8];
    #pragma unroll
    for (int r = 0; r < 8; r++) {
        ss[r] = specie[r * 512 + t];
        atomicAdd(&lcnt[ss[r]], 1);
    }
    __syncthreads();
    if (t == 0) {
        int acc = 0;
        for (int s = 0; s < NSPEC; s++) {
            lcur[s] = acc; cntoff[16 + s] = acc; cntoff[s] = lcnt[s]; acc += lcnt[s];
        }
    }
    __syncthreads();
    #pragma unroll
    for (int r = 0; r < 8; r++) {
        int pos = atomicAdd(&lcur[ss[r]], 1);
        glist[pos] = r * 512 + t;
    }
}

// ---------------------------------------------------------------------------
// Kernel 3: per-(s,c) monomial coefficients.
// coeff layout: [s*128+c][mono 0..218][og 0..3]
// ---------------------------------------------------------------------------
__global__ void k_coeff(const float* __restrict__ U3sym, const float* __restrict__ U2sym,
                        const float* __restrict__ U1_0e, const float* __restrict__ U1_1o,
                        const float* __restrict__ W3_0e, const float* __restrict__ W3_1o,
                        const float* __restrict__ W2_0e, const float* __restrict__ W2_1o,
                        const float* __restrict__ W1_0e, const float* __restrict__ W1_1o,
                        float* __restrict__ coeff) {
    int blk = blockIdx.x;            // s*128 + c
    int s = blk >> 7, c = blk & 127;
    int t = threadIdx.x;
    if (t >= NMONO * 4) return;
    int m = t >> 2, og = t & 3;
    float val;
    if (m < NCUB) {
        const float* W3 = (og == 0) ? W3_0e : W3_1o;   // [s][k][c] strides 512/128/1
        const float* u  = U3sym + (og * 165 + m) * 4;
        val = u[0] * W3[s*512 +       c] + u[1] * W3[s*512 + 128 + c]
            + u[2] * W3[s*512 + 256 + c] + u[3] * W3[s*512 + 384 + c];
    } else if (m < NCUB + NQUAD) {
        int q = m - NCUB;
        const float* W2 = (og == 0) ? W2_0e : W2_1o;   // [s][k][c] strides 256/128/1
        const float* u  = U2sym + (og * 45 + q) * 2;
        val = u[0] * W2[s*256 + c] + u[1] * W2[s*256 + 128 + c];
    } else {
        int l = m - (NCUB + NQUAD);
        const float* U1 = (og == 0) ? U1_0e : U1_1o;   // [o][i][k=1]
        const float* W1 = (og == 0) ? W1_0e : W1_1o;   // [s][1][c]
        int o = (og == 0) ? 0 : og - 1;
        val = U1[o * 9 + l] * W1[s * 128 + c];
    }
    coeff[(size_t)blk * 876 + t] = val;
}

// ---------------------------------------------------------------------------
// Kernel 4: gather+transpose x -> xg[ci][slot], slot = species-sorted order.
// All global accesses are >=256B contiguous runs.
// ---------------------------------------------------------------------------
__global__ __launch_bounds__(256) void k_gather(const float* __restrict__ x,
        const int* __restrict__ glist, float* __restrict__ xg) {
    __shared__ float tile[64][65];
    __shared__ int nodes[64];
    int bx = blockIdx.x;
    int st = bx / 18, ct = bx - st * 18;   // slot-tile(64 slots), ci-tile(64 of 1152)
    int t = threadIdx.x;
    if (t < 64) nodes[t] = glist[st * 64 + t];
    __syncthreads();
    #pragma unroll
    for (int r = 0; r < 4; ++r) {          // 64 sl x 16 float4
        int flat = r * 256 + t;
        int sl = flat >> 4, q = flat & 15;
        float4 v = *(const float4*)&x[(size_t)nodes[sl] * 1152 + ct * 64 + q * 4];
        tile[sl][q * 4 + 0] = v.x; tile[sl][q * 4 + 1] = v.y;
        tile[sl][q * 4 + 2] = v.z; tile[sl][q * 4 + 3] = v.w;
    }
    __syncthreads();
    #pragma unroll
    for (int r = 0; r < 16; ++r) {
        int flat = r * 256 + t;
        int ci = flat >> 6, sl = flat & 63;
        xg[(size_t)(ct * 64 + ci) * 4096 + st * 64 + sl] = tile[sl][ci];
    }
}

// ---------------------------------------------------------------------------
// Kernel 5: main contraction. Block=(s,c); coeffs staged once into LDS
// (876 floats, broadcast ds_read_b128 in the loop); x reads fully coalesced
// from xg; 2 nodes/thread. fg output: [e*128+c][slot] (coalesced stores).
// ---------------------------------------------------------------------------
__global__ __launch_bounds__(256, 4) void k_main(const float* __restrict__ xg,
        const int* __restrict__ cntoff, const float* __restrict__ coeff,
        float* __restrict__ fg) {
    __shared__ float cfs[880];
    int blk = blockIdx.x;
    int s = blk >> 7, c = blk & 127;
    const float* __restrict__ cf = coeff + (size_t)blk * 876;
    for (int j = threadIdx.x; j < 876; j += 256) cfs[j] = cf[j];
    int n   = cntoff[s];
    int off = cntoff[16 + s];
    __syncthreads();
    if (n == 0) return;

    for (int base = 0; base < n; base += 512) {
        int i0 = base + (int)threadIdx.x;
        int i1 = i0 + 256;
        int j0 = off + min(i0, n - 1);
        int j1 = off + min(i1, n - 1);
        float x0[9], x1[9];
        #pragma unroll
        for (int i = 0; i < 9; i++) {
            const float* row = xg + (size_t)(c * 9 + i) * 4096;
            x0[i] = row[j0];
            x1[i] = row[j1];
        }
        float a0[4] = {0.f,0.f,0.f,0.f}, a1[4] = {0.f,0.f,0.f,0.f};
        int m3 = 0, m2 = 0;
        #pragma unroll
        for (int a = 0; a < 9; a++) {
            {   // linear term
                float4 cl = *(const float4*)&cfs[(210 + a) * 4];
                a0[0] = fmaf(cl.x, x0[a], a0[0]); a1[0] = fmaf(cl.x, x1[a], a1[0]);
                a0[1] = fmaf(cl.y, x0[a], a0[1]); a1[1] = fmaf(cl.y, x1[a], a1[1]);
                a0[2] = fmaf(cl.z, x0[a], a0[2]); a1[2] = fmaf(cl.z, x1[a], a1[2]);
                a0[3] = fmaf(cl.w, x0[a], a0[3]); a1[3] = fmaf(cl.w, x1[a], a1[3]);
            }
            #pragma unroll
            for (int b = a; b < 9; b++) {
                float p0 = x0[a] * x0[b], p1 = x1[a] * x1[b];
                float4 cq = *(const float4*)&cfs[(165 + m2) * 4]; m2++;
                a0[0] = fmaf(cq.x, p0, a0[0]); a1[0] = fmaf(cq.x, p1, a1[0]);
                a0[1] = fmaf(cq.y, p0, a0[1]); a1[1] = fmaf(cq.y, p1, a1[1]);
                a0[2] = fmaf(cq.z, p0, a0[2]); a1[2] = fmaf(cq.z, p1, a1[2]);
                a0[3] = fmaf(cq.w, p0, a0[3]); a1[3] = fmaf(cq.w, p1, a1[3]);
                #pragma unroll
                for (int d = b; d < 9; d++) {
                    float4 c3 = *(const float4*)&cfs[m3 * 4]; m3++;
                    float q0 = p0 * x0[d], q1 = p1 * x1[d];
                    a0[0] = fmaf(c3.x, q0, a0[0]); a1[0] = fmaf(c3.x, q1, a1[0]);
                    a0[1] = fmaf(c3.y, q0, a0[1]); a1[1] = fmaf(c3.y, q1, a1[1]);
                    a0[2] = fmaf(c3.z, q0, a0[2]); a1[2] = fmaf(c3.z, q1, a1[2]);
                    a0[3] = fmaf(c3.w, q0, a0[3]); a1[3] = fmaf(c3.w, q1, a1[3]);
                }
            }
        }
        if (i0 < n) {
            #pragma unroll
            for (int e = 0; e < 4; e++) fg[(size_t)(e * 128 + c) * 4096 + j0] = a0[e];
        }
        if (i1 < n) {
            #pragma unroll
            for (int e = 0; e < 4; e++) fg[(size_t)(e * 128 + c) * 4096 + j1] = a1[e];
        }
    }
}

// ---------------------------------------------------------------------------
// Kernel 6: epilogue linear. Block=(slot-tile 64, jg 0..7); staging reads are
// fully coalesced from fg; output rows via glist (256B runs per row).
// ---------------------------------------------------------------------------
__global__ __launch_bounds__(256) void k_epi(const float* __restrict__ fg,
        const float* __restrict__ W0, const float* __restrict__ W1,
        const float* __restrict__ bias, const int* __restrict__ glist,
        float* __restrict__ out) {
    __shared__ float smem[128 * 65];
    __shared__ int nodes[64];
    int bx = blockIdx.x;
    int st = bx >> 3, jg = bx & 7;
    int s0 = st * 64;
    int t  = threadIdx.x;
    int o  = jg >> 1;                        // output component 0..3 (uniform)
    if (t < 64) nodes[t] = glist[s0 + t];
    #pragma unroll
    for (int r = 0; r < 32; ++r) {
        int flat = r * 256 + t;              // 8192 = 128c * 64sl
        int c = flat >> 6, sl = flat & 63;
        smem[c * 65 + sl] = fg[(size_t)(o * 128 + c) * 4096 + s0 + sl];
    }
    __syncthreads();

    int w    = __builtin_amdgcn_readfirstlane((int)(t >> 6));
    int lane = t & 63;
    int mb   = (jg & 1) * 64 + w * 16;       // wave's m base (uniform)
    const float* __restrict__ Wsel = (o == 0) ? W0 : W1;

    float acc[16];
    #pragma unroll
    for (int jj = 0; jj < 16; jj++) acc[jj] = 0.f;

    #pragma unroll 4
    for (int c = 0; c < 128; ++c) {
        float fv = smem[c * 65 + lane];
        #pragma unroll
        for (int jj = 0; jj < 16; jj++)
            acc[jj] = fmaf(fv, Wsel[c * 128 + mb + jj], acc[jj]);
    }
    __syncthreads();

    const float scale = 0.08838834764831845f; // 1/sqrt(128)
    #pragma unroll
    for (int jj = 0; jj < 16; jj++) {
        float v = acc[jj] * scale;
        if (o == 0) v += bias[mb + jj];
        smem[(w * 16 + jj) * 65 + lane] = v;  // trbuf[j_local][slot]
    }
    __syncthreads();

    #pragma unroll
    for (int r = 0; r < 16; ++r) {
        int flat = r * 256 + t;               // 4096 = 64j * 64sl
        int jl = flat & 63, nn = flat >> 6;
        int m  = (jg & 1) * 64 + jl;
        int col = (o == 0) ? m : (128 + m * 3 + (o - 1));
        out[(size_t)nodes[nn] * 512 + col] = smem[jl * 65 + nn];
    }
}

extern "C" void kernel_launch(void* const* d_in, const int* in_sizes, int n_in,
                              void* d_out, int out_size, void* d_ws, size_t ws_size,
                              hipStream_t stream) {
    const float* x     = (const float*)d_in[0];
    const int*   spec  = (const int*)  d_in[1];
    const float* U3_0e = (const float*)d_in[2];
    const float* U2_0e = (const float*)d_in[3];
    const float* U1_0e = (const float*)d_in[4];
    const float* W3_0e = (const float*)d_in[5];
    const float* W2_0e = (const float*)d_in[6];
    const float* W1_0e = (const float*)d_in[7];
    const float* U3_1o = (const float*)d_in[8];
    const float* U2_1o = (const float*)d_in[9];
    const float* U1_1o = (const float*)d_in[10];
    const float* W3_1o = (const float*)d_in[11];
    const float* W2_1o = (const float*)d_in[12];
    const float* W1_1o = (const float*)d_in[13];
    const float* Wlin0 = (const float*)d_in[14];
    const float* Wlin1 = (const float*)d_in[15];
    const float* bias0 = (const float*)d_in[16];
    float* out = (float*)d_out;

    char* ws = (char*)d_ws;
    int*   cntoff = (int*)  (ws + WS_CNTOFF);
    int*   glist  = (int*)  (ws + WS_GLIST);
    float* U3sym  = (float*)(ws + WS_U3SYM);
    float* U2sym  = (float*)(ws + WS_U2SYM);
    float* coeff  = (float*)(ws + WS_COEFF);
    float* xg     = (float*)(ws + WS_XG);
    float* fg     = (float*)(ws + WS_FG);
    (void)in_sizes; (void)n_in; (void)out_size; (void)ws_size;

    hipLaunchKernelGGL(k_prep,   dim3(8),    dim3(384), 0, stream,
                       U3_0e, U3_1o, U2_0e, U2_1o, U3sym, U2sym);
    hipLaunchKernelGGL(k_sort,   dim3(1),    dim3(512), 0, stream, spec, cntoff, glist);
    hipLaunchKernelGGL(k_coeff,  dim3(1280), dim3(896), 0, stream,
                       U3sym, U2sym, U1_0e, U1_1o, W3_0e, W3_1o,
                       W2_0e, W2_1o, W1_0e, W1_1o, coeff);
    hipLaunchKernelGGL(k_gather, dim3(1152), dim3(256), 0, stream, x, glist, xg);
    hipLaunchKernelGGL(k_main,   dim3(1280), dim3(256), 0, stream, xg, cntoff, coeff, fg);
    hipLaunchKernelGGL(k_epi,    dim3(512),  dim3(256), 0, stream, fg, Wlin0, Wlin1, bias0, glist, out);
}

// Round 3
// 1128.539 us; speedup vs baseline: 1.2838x; 1.2838x over previous
//
#include <hip/hip_runtime.h>

#define N_NODES 4096
#define C_CH    128
#define NSPEC   10
#define NCUB    165
#define NQUAD   45
#define NMONO   219   // 165 cubic + 45 quad + 9 linear

// ---- workspace layout (bytes) ----
// cnt[10] ints at +0, off[10] ints at +64 (int index 16)
#define WS_CNTOFF 0
#define WS_GLIST  256                       // 4096 ints = 16384
#define WS_U3SYM  16640                     // 4og*165*4k floats = 10560
#define WS_U2SYM  27200                     // 4og*45*2k  floats = 1440
#define WS_COEFF  28672                     // 1280*876 floats = 4485120
#define WS_XG     4513792                   // 1152*4096 floats = 18874368
#define WS_FG     23388160                  // 512*4096 floats  = 8388608
// total ~31.8 MB

// ---------------------------------------------------------------------------
// Kernel 1: permutation-symmetrized U3/U2 (tiny, spread over 8 blocks).
// ---------------------------------------------------------------------------
__global__ void k_prep(const float* __restrict__ U3_0e, const float* __restrict__ U3_1o,
                       const float* __restrict__ U2_0e, const float* __restrict__ U2_1o,
                       float* __restrict__ U3sym, float* __restrict__ U2sym) {
    int task = blockIdx.x * 384 + threadIdx.x;
    if (task >= 2640 + 360) return;
    if (task < 2640) {               // cubic: og(4) * m(165) * k(4)
        int og = task / 660;
        int r  = task - og * 660;
        int m  = r >> 2, k = r & 3;
        int a = 0, b = 0, d = 0;
        {   int idx = 0;
            for (int a0 = 0; a0 < 9; a0++)
                for (int b0 = a0; b0 < 9; b0++)
                    for (int d0 = b0; d0 < 9; d0++) {
                        if (idx == m) { a = a0; b = b0; d = d0; }
                        idx++;
                    }
        }
        const float* U3 = (og == 0) ? U3_0e : U3_1o;
        int o = (og == 0) ? 0 : og - 1;
        const float* Ub = U3 + (size_t)o * 2916;   // [p][q][i][k] strides 324/36/4/1
        #define U3AT(p,q,i) Ub[((p)*9+(q))*36 + (i)*4 + k]
        float sum = U3AT(a,b,d) + U3AT(a,d,b) + U3AT(b,a,d)
                  + U3AT(b,d,a) + U3AT(d,a,b) + U3AT(d,b,a);
        #undef U3AT
        float sc = (a == b && b == d) ? (1.f/6.f)
                 : ((a == b || b == d || a == d) ? 0.5f : 1.f);
        U3sym[(og * 165 + m) * 4 + k] = sum * sc;
    } else {                          // quad: og(4) * q(45) * k(2)
        int t2 = task - 2640;
        int og = t2 / 90;
        int r  = t2 - og * 90;
        int q  = r >> 1, k = r & 1;
        int a = 0, b = 0;
        {   int idx = 0;
            for (int a0 = 0; a0 < 9; a0++)
                for (int b0 = a0; b0 < 9; b0++) { if (idx == q) { a = a0; b = b0; } idx++; }
        }
        const float* U2 = (og == 0) ? U2_0e : U2_1o;
        int o = (og == 0) ? 0 : og - 1;
        const float* Ub = U2 + (size_t)o * 162;    // [p][i][k] strides 18/2/1
        float sum = Ub[(a*9 + b)*2 + k] + Ub[(b*9 + a)*2 + k];
        if (a == b) sum *= 0.5f;
        U2sym[(og * 45 + q) * 2 + k] = sum;
    }
}

// ---------------------------------------------------------------------------
// Kernel 2: single-block species sort: counts, prefix offsets, sorted list.
// ---------------------------------------------------------------------------
__global__ __launch_bounds__(512) void k_sort(const int* __restrict__ specie,
        int* __restrict__ cntoff, int* __restrict__ glist) {
    __shared__ int lcnt[NSPEC], lcur[NSPEC];
    int t = threadIdx.x;
    if (t < NSPEC) lcnt[t] = 0;
    __syncthreads();
    int ss[8];
    #pragma unroll
    for (int r = 0; r < 8; r++) {
        ss[r] = specie[r * 512 + t];
        atomicAdd(&lcnt[ss[r]], 1);
    }
    __syncthreads();
    if (t == 0) {
        int acc = 0;
        for (int s = 0; s < NSPEC; s++) {
            lcur[s] = acc; cntoff[16 + s] = acc; cntoff[s] = lcnt[s]; acc += lcnt[s];
        }
    }
    __syncthreads();
    #pragma unroll
    for (int r = 0; r < 8; r++) {
        int pos = atomicAdd(&lcur[ss[r]], 1);
        glist[pos] = r * 512 + t;
    }
}

// ---------------------------------------------------------------------------
// Kernel 3: per-(s,c) monomial coefficients.
// coeff layout: [s*128+c][mono 0..218][og 0..3]
// ---------------------------------------------------------------------------
__global__ void k_coeff(const float* __restrict__ U3sym, const float* __restrict__ U2sym,
                        const float* __restrict__ U1_0e, const float* __restrict__ U1_1o,
                        const float* __restrict__ W3_0e, const float* __restrict__ W3_1o,
                        const float* __restrict__ W2_0e, const float* __restrict__ W2_1o,
                        const float* __restrict__ W1_0e, const float* __restrict__ W1_1o,
                        float* __restrict__ coeff) {
    int blk = blockIdx.x;            // s*128 + c
    int s = blk >> 7, c = blk & 127;
    int t = threadIdx.x;
    if (t >= NMONO * 4) return;
    int m = t >> 2, og = t & 3;
    float val;
    if (m < NCUB) {
        const float* W3 = (og == 0) ? W3_0e : W3_1o;   // [s][k][c] strides 512/128/1
        const float* u  = U3sym + (og * 165 + m) * 4;
        val = u[0] * W3[s*512 +       c] + u[1] * W3[s*512 + 128 + c]
            + u[2] * W3[s*512 + 256 + c] + u[3] * W3[s*512 + 384 + c];
    } else if (m < NCUB + NQUAD) {
        int q = m - NCUB;
        const float* W2 = (og == 0) ? W2_0e : W2_1o;   // [s][k][c] strides 256/128/1
        const float* u  = U2sym + (og * 45 + q) * 2;
        val = u[0] * W2[s*256 + c] + u[1] * W2[s*256 + 128 + c];
    } else {
        int l = m - (NCUB + NQUAD);
        const float* U1 = (og == 0) ? U1_0e : U1_1o;   // [o][i][k=1]
        const float* W1 = (og == 0) ? W1_0e : W1_1o;   // [s][1][c]
        int o = (og == 0) ? 0 : og - 1;
        val = U1[o * 9 + l] * W1[s * 128 + c];
    }
    coeff[(size_t)blk * 876 + t] = val;
}

// ---------------------------------------------------------------------------
// Kernel 4: gather+transpose x -> xg[ci][slot], slot = species-sorted order.
// All global accesses are >=256B contiguous runs.
// ---------------------------------------------------------------------------
__global__ __launch_bounds__(256) void k_gather(const float* __restrict__ x,
        const int* __restrict__ glist, float* __restrict__ xg) {
    __shared__ float tile[64][65];
    __shared__ int nodes[64];
    int bx = blockIdx.x;
    int st = bx / 18, ct = bx - st * 18;   // slot-tile(64 slots), ci-tile(64 of 1152)
    int t = threadIdx.x;
    if (t < 64) nodes[t] = glist[st * 64 + t];
    __syncthreads();
    #pragma unroll
    for (int r = 0; r < 4; ++r) {          // 64 sl x 16 float4
        int flat = r * 256 + t;
        int sl = flat >> 4, q = flat & 15;
        float4 v = *(const float4*)&x[(size_t)nodes[sl] * 1152 + ct * 64 + q * 4];
        tile[sl][q * 4 + 0] = v.x; tile[sl][q * 4 + 1] = v.y;
        tile[sl][q * 4 + 2] = v.z; tile[sl][q * 4 + 3] = v.w;
    }
    __syncthreads();
    #pragma unroll
    for (int r = 0; r < 16; ++r) {
        int flat = r * 256 + t;
        int ci = flat >> 6, sl = flat & 63;
        xg[(size_t)(ct * 64 + ci) * 4096 + st * 64 + sl] = tile[sl][ci];
    }
}

// ---------------------------------------------------------------------------
// Kernel 5: main contraction. Block=(s,c); coeffs staged once into LDS
// (876 floats, broadcast ds_read_b128 in the loop); x reads fully coalesced
// from xg; 2 nodes/thread. fg output: [e*128+c][slot] (coalesced stores).
// NOTE: plain __launch_bounds__(256) — adding a min-waves arg (",4") caps
// VGPRs at 128 and the ~7000-instr unrolled body spills to scratch
// (round 2: VGPR 64, 2 GB scratch traffic, 9x regression). Do not re-add.
// ---------------------------------------------------------------------------
__global__ __launch_bounds__(256) void k_main(const float* __restrict__ xg,
        const int* __restrict__ cntoff, const float* __restrict__ coeff,
        float* __restrict__ fg) {
    __shared__ float cfs[880];
    int blk = blockIdx.x;
    int s = blk >> 7, c = blk & 127;
    const float* __restrict__ cf = coeff + (size_t)blk * 876;
    for (int j = threadIdx.x; j < 876; j += 256) cfs[j] = cf[j];
    int n   = cntoff[s];
    int off = cntoff[16 + s];
    __syncthreads();
    if (n == 0) return;

    for (int base = 0; base < n; base += 512) {
        int i0 = base + (int)threadIdx.x;
        int i1 = i0 + 256;
        int j0 = off + min(i0, n - 1);
        int j1 = off + min(i1, n - 1);
        float x0[9], x1[9];
        #pragma unroll
        for (int i = 0; i < 9; i++) {
            const float* row = xg + (size_t)(c * 9 + i) * 4096;
            x0[i] = row[j0];
            x1[i] = row[j1];
        }
        float a0[4] = {0.f,0.f,0.f,0.f}, a1[4] = {0.f,0.f,0.f,0.f};
        int m3 = 0, m2 = 0;
        #pragma unroll
        for (int a = 0; a < 9; a++) {
            {   // linear term
                float4 cl = *(const float4*)&cfs[(210 + a) * 4];
                a0[0] = fmaf(cl.x, x0[a], a0[0]); a1[0] = fmaf(cl.x, x1[a], a1[0]);
                a0[1] = fmaf(cl.y, x0[a], a0[1]); a1[1] = fmaf(cl.y, x1[a], a1[1]);
                a0[2] = fmaf(cl.z, x0[a], a0[2]); a1[2] = fmaf(cl.z, x1[a], a1[2]);
                a0[3] = fmaf(cl.w, x0[a], a0[3]); a1[3] = fmaf(cl.w, x1[a], a1[3]);
            }
            #pragma unroll
            for (int b = a; b < 9; b++) {
                float p0 = x0[a] * x0[b], p1 = x1[a] * x1[b];
                float4 cq = *(const float4*)&cfs[(165 + m2) * 4]; m2++;
                a0[0] = fmaf(cq.x, p0, a0[0]); a1[0] = fmaf(cq.x, p1, a1[0]);
                a0[1] = fmaf(cq.y, p0, a0[1]); a1[1] = fmaf(cq.y, p1, a1[1]);
                a0[2] = fmaf(cq.z, p0, a0[2]); a1[2] = fmaf(cq.z, p1, a1[2]);
                a0[3] = fmaf(cq.w, p0, a0[3]); a1[3] = fmaf(cq.w, p1, a1[3]);
                #pragma unroll
                for (int d = b; d < 9; d++) {
                    float4 c3 = *(const float4*)&cfs[m3 * 4]; m3++;
                    float q0 = p0 * x0[d], q1 = p1 * x1[d];
                    a0[0] = fmaf(c3.x, q0, a0[0]); a1[0] = fmaf(c3.x, q1, a1[0]);
                    a0[1] = fmaf(c3.y, q0, a0[1]); a1[1] = fmaf(c3.y, q1, a1[1]);
                    a0[2] = fmaf(c3.z, q0, a0[2]); a1[2] = fmaf(c3.z, q1, a1[2]);
                    a0[3] = fmaf(c3.w, q0, a0[3]); a1[3] = fmaf(c3.w, q1, a1[3]);
                }
            }
        }
        if (i0 < n) {
            #pragma unroll
            for (int e = 0; e < 4; e++) fg[(size_t)(e * 128 + c) * 4096 + j0] = a0[e];
        }
        if (i1 < n) {
            #pragma unroll
            for (int e = 0; e < 4; e++) fg[(size_t)(e * 128 + c) * 4096 + j1] = a1[e];
        }
    }
}

// ---------------------------------------------------------------------------
// Kernel 6: epilogue linear. Block=(slot-tile 64, jg 0..7); staging reads are
// fully coalesced from fg; output rows via glist (256B runs per row).
// ---------------------------------------------------------------------------
__global__ __launch_bounds__(256) void k_epi(const float* __restrict__ fg,
        const float* __restrict__ W0, const float* __restrict__ W1,
        const float* __restrict__ bias, const int* __restrict__ glist,
        float* __restrict__ out) {
    __shared__ float smem[128 * 65];
    __shared__ int nodes[64];
    int bx = blockIdx.x;
    int st = bx >> 3, jg = bx & 7;
    int s0 = st * 64;
    int t  = threadIdx.x;
    int o  = jg >> 1;                        // output component 0..3 (uniform)
    if (t < 64) nodes[t] = glist[s0 + t];
    #pragma unroll
    for (int r = 0; r < 32; ++r) {
        int flat = r * 256 + t;              // 8192 = 128c * 64sl
        int c = flat >> 6, sl = flat & 63;
        smem[c * 65 + sl] = fg[(size_t)(o * 128 + c) * 4096 + s0 + sl];
    }
    __syncthreads();

    int w    = __builtin_amdgcn_readfirstlane((int)(t >> 6));
    int lane = t & 63;
    int mb   = (jg & 1) * 64 + w * 16;       // wave's m base (uniform)
    const float* __restrict__ Wsel = (o == 0) ? W0 : W1;

    float acc[16];
    #pragma unroll
    for (int jj = 0; jj < 16; jj++) acc[jj] = 0.f;

    #pragma unroll 4
    for (int c = 0; c < 128; ++c) {
        float fv = smem[c * 65 + lane];
        #pragma unroll
        for (int jj = 0; jj < 16; jj++)
            acc[jj] = fmaf(fv, Wsel[c * 128 + mb + jj], acc[jj]);
    }
    __syncthreads();

    const float scale = 0.08838834764831845f; // 1/sqrt(128)
    #pragma unroll
    for (int jj = 0; jj < 16; jj++) {
        float v = acc[jj] * scale;
        if (o == 0) v += bias[mb + jj];
        smem[(w * 16 + jj) * 65 + lane] = v;  // trbuf[j_local][slot]
    }
    __syncthreads();

    #pragma unroll
    for (int r = 0; r < 16; ++r) {
        int flat = r * 256 + t;               // 4096 = 64j * 64sl
        int jl = flat & 63, nn = flat >> 6;
        int m  = (jg & 1) * 64 + jl;
        int col = (o == 0) ? m : (128 + m * 3 + (o - 1));
        out[(size_t)nodes[nn] * 512 + col] = smem[jl * 65 + nn];
    }
}

extern "C" void kernel_launch(void* const* d_in, const int* in_sizes, int n_in,
                              void* d_out, int out_size, void* d_ws, size_t ws_size,
                              hipStream_t stream) {
    const float* x     = (const float*)d_in[0];
    const int*   spec  = (const int*)  d_in[1];
    const float* U3_0e = (const float*)d_in[2];
    const float* U2_0e = (const float*)d_in[3];
    const float* U1_0e = (const float*)d_in[4];
    const float* W3_0e = (const float*)d_in[5];
    const float* W2_0e = (const float*)d_in[6];
    const float* W1_0e = (const float*)d_in[7];
    const float* U3_1o = (const float*)d_in[8];
    const float* U2_1o = (const float*)d_in[9];
    const float* U1_1o = (const float*)d_in[10];
    const float* W3_1o = (const float*)d_in[11];
    const float* W2_1o = (const float*)d_in[12];
    const float* W1_1o = (const float*)d_in[13];
    const float* Wlin0 = (const float*)d_in[14];
    const float* Wlin1 = (const float*)d_in[15];
    const float* bias0 = (const float*)d_in[16];
    float* out = (float*)d_out;

    char* ws = (char*)d_ws;
    int*   cntoff = (int*)  (ws + WS_CNTOFF);
    int*   glist  = (int*)  (ws + WS_GLIST);
    float* U3sym  = (float*)(ws + WS_U3SYM);
    float* U2sym  = (float*)(ws + WS_U2SYM);
    float* coeff  = (float*)(ws + WS_COEFF);
    float* xg     = (float*)(ws + WS_XG);
    float* fg     = (float*)(ws + WS_FG);
    (void)in_sizes; (void)n_in; (void)out_size; (void)ws_size;

    hipLaunchKernelGGL(k_prep,   dim3(8),    dim3(384), 0, stream,
                       U3_0e, U3_1o, U2_0e, U2_1o, U3sym, U2sym);
    hipLaunchKernelGGL(k_sort,   dim3(1),    dim3(512), 0, stream, spec, cntoff, glist);
    hipLaunchKernelGGL(k_coeff,  dim3(1280), dim3(896), 0, stream,
                       U3sym, U2sym, U1_0e, U1_1o, W3_0e, W3_1o,
                       W2_0e, W2_1o, W1_0e, W1_1o, coeff);
    hipLaunchKernelGGL(k_gather, dim3(1152), dim3(256), 0, stream, x, glist, xg);
    hipLaunchKernelGGL(k_main,   dim3(1280), dim3(256), 0, stream, xg, cntoff, coeff, fg);
    hipLaunchKernelGGL(k_epi,    dim3(512),  dim3(256), 0, stream, fg, Wlin0, Wlin1, bias0, glist, out);
}

// Round 4
// 319.531 us; speedup vs baseline: 4.5344x; 3.5319x over previous
//
#include <hip/hip_runtime.h>

#define N_NODES 4096
#define C_CH    128
#define NSPEC   10
#define NCUB    165
#define NQUAD   45
#define NMONO   219   // 165 cubic + 45 quad + 9 linear

// ---- workspace layout (bytes) ----
// cnt[10] ints at +0, off[10] ints at +64 (int index 16)
#define WS_CNTOFF 0
#define WS_GLIST  256                       // 4096 ints = 16384
#define WS_U3SYM  16640                     // 4og*165*4k floats = 10560
#define WS_U2SYM  27200                     // 4og*45*2k  floats = 1440
#define WS_COEFF  28672                     // 1280*876 floats = 4485120
#define WS_XG     4513792                   // 1152*4096 floats = 18874368
#define WS_FG     23388160                  // 512*4096 floats  = 8388608
// total ~31.8 MB

// ---------------------------------------------------------------------------
// Kernel 1: permutation-symmetrized U3/U2 (tiny, spread over 8 blocks).
// ---------------------------------------------------------------------------
__global__ void k_prep(const float* __restrict__ U3_0e, const float* __restrict__ U3_1o,
                       const float* __restrict__ U2_0e, const float* __restrict__ U2_1o,
                       float* __restrict__ U3sym, float* __restrict__ U2sym) {
    int task = blockIdx.x * 384 + threadIdx.x;
    if (task >= 2640 + 360) return;
    if (task < 2640) {               // cubic: og(4) * m(165) * k(4)
        int og = task / 660;
        int r  = task - og * 660;
        int m  = r >> 2, k = r & 3;
        int a = 0, b = 0, d = 0;
        {   int idx = 0;
            for (int a0 = 0; a0 < 9; a0++)
                for (int b0 = a0; b0 < 9; b0++)
                    for (int d0 = b0; d0 < 9; d0++) {
                        if (idx == m) { a = a0; b = b0; d = d0; }
                        idx++;
                    }
        }
        const float* U3 = (og == 0) ? U3_0e : U3_1o;
        int o = (og == 0) ? 0 : og - 1;
        const float* Ub = U3 + (size_t)o * 2916;   // [p][q][i][k] strides 324/36/4/1
        #define U3AT(p,q,i) Ub[((p)*9+(q))*36 + (i)*4 + k]
        float sum = U3AT(a,b,d) + U3AT(a,d,b) + U3AT(b,a,d)
                  + U3AT(b,d,a) + U3AT(d,a,b) + U3AT(d,b,a);
        #undef U3AT
        float sc = (a == b && b == d) ? (1.f/6.f)
                 : ((a == b || b == d || a == d) ? 0.5f : 1.f);
        U3sym[(og * 165 + m) * 4 + k] = sum * sc;
    } else {                          // quad: og(4) * q(45) * k(2)
        int t2 = task - 2640;
        int og = t2 / 90;
        int r  = t2 - og * 90;
        int q  = r >> 1, k = r & 1;
        int a = 0, b = 0;
        {   int idx = 0;
            for (int a0 = 0; a0 < 9; a0++)
                for (int b0 = a0; b0 < 9; b0++) { if (idx == q) { a = a0; b = b0; } idx++; }
        }
        const float* U2 = (og == 0) ? U2_0e : U2_1o;
        int o = (og == 0) ? 0 : og - 1;
        const float* Ub = U2 + (size_t)o * 162;    // [p][i][k] strides 18/2/1
        float sum = Ub[(a*9 + b)*2 + k] + Ub[(b*9 + a)*2 + k];
        if (a == b) sum *= 0.5f;
        U2sym[(og * 45 + q) * 2 + k] = sum;
    }
}

// ---------------------------------------------------------------------------
// Kernel 2: single-block species sort: counts, prefix offsets, sorted list.
// ---------------------------------------------------------------------------
__global__ __launch_bounds__(512) void k_sort(const int* __restrict__ specie,
        int* __restrict__ cntoff, int* __restrict__ glist) {
    __shared__ int lcnt[NSPEC], lcur[NSPEC];
    int t = threadIdx.x;
    if (t < NSPEC) lcnt[t] = 0;
    __syncthreads();
    int ss[8];
    #pragma unroll
    for (int r = 0; r < 8; r++) {
        ss[r] = specie[r * 512 + t];
        atomicAdd(&lcnt[ss[r]], 1);
    }
    __syncthreads();
    if (t == 0) {
        int acc = 0;
        for (int s = 0; s < NSPEC; s++) {
            lcur[s] = acc; cntoff[16 + s] = acc; cntoff[s] = lcnt[s]; acc += lcnt[s];
        }
    }
    __syncthreads();
    #pragma unroll
    for (int r = 0; r < 8; r++) {
        int pos = atomicAdd(&lcur[ss[r]], 1);
        glist[pos] = r * 512 + t;
    }
}

// ---------------------------------------------------------------------------
// Kernel 3: per-(s,c) monomial coefficients.
// coeff layout: [s*128+c][mono 0..218][og 0..3]
// ---------------------------------------------------------------------------
__global__ void k_coeff(const float* __restrict__ U3sym, const float* __restrict__ U2sym,
                        const float* __restrict__ U1_0e, const float* __restrict__ U1_1o,
                        const float* __restrict__ W3_0e, const float* __restrict__ W3_1o,
                        const float* __restrict__ W2_0e, const float* __restrict__ W2_1o,
                        const float* __restrict__ W1_0e, const float* __restrict__ W1_1o,
                        float* __restrict__ coeff) {
    int blk = blockIdx.x;            // s*128 + c
    int s = blk >> 7, c = blk & 127;
    int t = threadIdx.x;
    if (t >= NMONO * 4) return;
    int m = t >> 2, og = t & 3;
    float val;
    if (m < NCUB) {
        const float* W3 = (og == 0) ? W3_0e : W3_1o;   // [s][k][c] strides 512/128/1
        const float* u  = U3sym + (og * 165 + m) * 4;
        val = u[0] * W3[s*512 +       c] + u[1] * W3[s*512 + 128 + c]
            + u[2] * W3[s*512 + 256 + c] + u[3] * W3[s*512 + 384 + c];
    } else if (m < NCUB + NQUAD) {
        int q = m - NCUB;
        const float* W2 = (og == 0) ? W2_0e : W2_1o;   // [s][k][c] strides 256/128/1
        const float* u  = U2sym + (og * 45 + q) * 2;
        val = u[0] * W2[s*256 + c] + u[1] * W2[s*256 + 128 + c];
    } else {
        int l = m - (NCUB + NQUAD);
        const float* U1 = (og == 0) ? U1_0e : U1_1o;   // [o][i][k=1]
        const float* W1 = (og == 0) ? W1_0e : W1_1o;   // [s][1][c]
        int o = (og == 0) ? 0 : og - 1;
        val = U1[o * 9 + l] * W1[s * 128 + c];
    }
    coeff[(size_t)blk * 876 + t] = val;
}

// ---------------------------------------------------------------------------
// Kernel 4: gather+transpose x -> xg[ci][slot], slot = species-sorted order.
// All global accesses are >=256B contiguous runs.
// ---------------------------------------------------------------------------
__global__ __launch_bounds__(256) void k_gather(const float* __restrict__ x,
        const int* __restrict__ glist, float* __restrict__ xg) {
    __shared__ float tile[64][65];
    __shared__ int nodes[64];
    int bx = blockIdx.x;
    int st = bx / 18, ct = bx - st * 18;   // slot-tile(64 slots), ci-tile(64 of 1152)
    int t = threadIdx.x;
    if (t < 64) nodes[t] = glist[st * 64 + t];
    __syncthreads();
    #pragma unroll
    for (int r = 0; r < 4; ++r) {          // 64 sl x 16 float4
        int flat = r * 256 + t;
        int sl = flat >> 4, q = flat & 15;
        float4 v = *(const float4*)&x[(size_t)nodes[sl] * 1152 + ct * 64 + q * 4];
        tile[sl][q * 4 + 0] = v.x; tile[sl][q * 4 + 1] = v.y;
        tile[sl][q * 4 + 2] = v.z; tile[sl][q * 4 + 3] = v.w;
    }
    __syncthreads();
    #pragma unroll
    for (int r = 0; r < 16; ++r) {
        int flat = r * 256 + t;
        int ci = flat >> 6, sl = flat & 63;
        xg[(size_t)(ct * 64 + ci) * 4096 + st * 64 + sl] = tile[sl][ci];
    }
}

// ---------------------------------------------------------------------------
// Kernel 5: main contraction. Block=(s,c).
// Coefficients are read DIRECTLY FROM GLOBAL through a wave-uniform pointer:
// the compiler emits a scalar (s_load/SGPR) stream — no VGPR pressure, no
// spill (round 1 evidence: VGPR 144, SGPR 112, zero scratch).
// DO NOT stage coeffs in LDS as float4: the scheduler hoists ds_read_b128s
// and spills ~1.2 GB to scratch (rounds 2-3, 7-9x regression).
// DO NOT add a min-waves arg to __launch_bounds__ (round 2).
// x reads fully coalesced from xg; fg stores coalesced: [e*128+c][slot].
// ---------------------------------------------------------------------------
__global__ __launch_bounds__(256) void k_main(const float* __restrict__ xg,
        const int* __restrict__ cntoff, const float* __restrict__ coeff,
        float* __restrict__ fg) {
    int blk = blockIdx.x;
    int s = blk >> 7, c = blk & 127;
    const float* __restrict__ cf = coeff + (size_t)blk * 876;   // wave-uniform
    int n   = cntoff[s];
    int off = cntoff[16 + s];
    if (n == 0) return;

    for (int base = 0; base < n; base += 512) {
        int i0 = base + (int)threadIdx.x;
        int i1 = i0 + 256;
        int j0 = off + min(i0, n - 1);
        int j1 = off + min(i1, n - 1);
        float x0[9], x1[9];
        #pragma unroll
        for (int i = 0; i < 9; i++) {
            const float* row = xg + (size_t)(c * 9 + i) * 4096;
            x0[i] = row[j0];
            x1[i] = row[j1];
        }
        float a0[4] = {0.f,0.f,0.f,0.f}, a1[4] = {0.f,0.f,0.f,0.f};
        int m3 = 0, m2 = 0;
        #pragma unroll
        for (int a = 0; a < 9; a++) {
            {   // linear term
                const float* cl = cf + (210 + a) * 4;
                #pragma unroll
                for (int e = 0; e < 4; e++) { a0[e] = fmaf(cl[e], x0[a], a0[e]);
                                              a1[e] = fmaf(cl[e], x1[a], a1[e]); }
            }
            #pragma unroll
            for (int b = a; b < 9; b++) {
                float p0 = x0[a] * x0[b], p1 = x1[a] * x1[b];
                const float* cq = cf + (165 + m2) * 4; m2++;
                #pragma unroll
                for (int e = 0; e < 4; e++) { a0[e] = fmaf(cq[e], p0, a0[e]);
                                              a1[e] = fmaf(cq[e], p1, a1[e]); }
                #pragma unroll
                for (int d = b; d < 9; d++) {
                    const float* c3 = cf + m3 * 4; m3++;
                    float q0 = p0 * x0[d], q1 = p1 * x1[d];
                    #pragma unroll
                    for (int e = 0; e < 4; e++) { a0[e] = fmaf(c3[e], q0, a0[e]);
                                                  a1[e] = fmaf(c3[e], q1, a1[e]); }
                }
            }
        }
        if (i0 < n) {
            #pragma unroll
            for (int e = 0; e < 4; e++) fg[(size_t)(e * 128 + c) * 4096 + j0] = a0[e];
        }
        if (i1 < n) {
            #pragma unroll
            for (int e = 0; e < 4; e++) fg[(size_t)(e * 128 + c) * 4096 + j1] = a1[e];
        }
    }
}

// ---------------------------------------------------------------------------
// Kernel 6: epilogue linear. Block=(slot-tile 64, jg 0..7); staging reads are
// fully coalesced from fg; output rows via glist (256B runs per row).
// ---------------------------------------------------------------------------
__global__ __launch_bounds__(256) void k_epi(const float* __restrict__ fg,
        const float* __restrict__ W0, const float* __restrict__ W1,
        const float* __restrict__ bias, const int* __restrict__ glist,
        float* __restrict__ out) {
    __shared__ float smem[128 * 65];
    __shared__ int nodes[64];
    int bx = blockIdx.x;
    int st = bx >> 3, jg = bx & 7;
    int s0 = st * 64;
    int t  = threadIdx.x;
    int o  = jg >> 1;                        // output component 0..3 (uniform)
    if (t < 64) nodes[t] = glist[s0 + t];
    #pragma unroll
    for (int r = 0; r < 32; ++r) {
        int flat = r * 256 + t;              // 8192 = 128c * 64sl
        int c = flat >> 6, sl = flat & 63;
        smem[c * 65 + sl] = fg[(size_t)(o * 128 + c) * 4096 + s0 + sl];
    }
    __syncthreads();

    int w    = __builtin_amdgcn_readfirstlane((int)(t >> 6));
    int lane = t & 63;
    int mb   = (jg & 1) * 64 + w * 16;       // wave's m base (uniform)
    const float* __restrict__ Wsel = (o == 0) ? W0 : W1;

    float acc[16];
    #pragma unroll
    for (int jj = 0; jj < 16; jj++) acc[jj] = 0.f;

    #pragma unroll 4
    for (int c = 0; c < 128; ++c) {
        float fv = smem[c * 65 + lane];
        #pragma unroll
        for (int jj = 0; jj < 16; jj++)
            acc[jj] = fmaf(fv, Wsel[c * 128 + mb + jj], acc[jj]);
    }
    __syncthreads();

    const float scale = 0.08838834764831845f; // 1/sqrt(128)
    #pragma unroll
    for (int jj = 0; jj < 16; jj++) {
        float v = acc[jj] * scale;
        if (o == 0) v += bias[mb + jj];
        smem[(w * 16 + jj) * 65 + lane] = v;  // trbuf[j_local][slot]
    }
    __syncthreads();

    #pragma unroll
    for (int r = 0; r < 16; ++r) {
        int flat = r * 256 + t;               // 4096 = 64j * 64sl
        int jl = flat & 63, nn = flat >> 6;
        int m  = (jg & 1) * 64 + jl;
        int col = (o == 0) ? m : (128 + m * 3 + (o - 1));
        out[(size_t)nodes[nn] * 512 + col] = smem[jl * 65 + nn];
    }
}

extern "C" void kernel_launch(void* const* d_in, const int* in_sizes, int n_in,
                              void* d_out, int out_size, void* d_ws, size_t ws_size,
                              hipStream_t stream) {
    const float* x     = (const float*)d_in[0];
    const int*   spec  = (const int*)  d_in[1];
    const float* U3_0e = (const float*)d_in[2];
    const float* U2_0e = (const float*)d_in[3];
    const float* U1_0e = (const float*)d_in[4];
    const float* W3_0e = (const float*)d_in[5];
    const float* W2_0e = (const float*)d_in[6];
    const float* W1_0e = (const float*)d_in[7];
    const float* U3_1o = (const float*)d_in[8];
    const float* U2_1o = (const float*)d_in[9];
    const float* U1_1o = (const float*)d_in[10];
    const float* W3_1o = (const float*)d_in[11];
    const float* W2_1o = (const float*)d_in[12];
    const float* W1_1o = (const float*)d_in[13];
    const float* Wlin0 = (const float*)d_in[14];
    const float* Wlin1 = (const float*)d_in[15];
    const float* bias0 = (const float*)d_in[16];
    float* out = (float*)d_out;

    char* ws = (char*)d_ws;
    int*   cntoff = (int*)  (ws + WS_CNTOFF);
    int*   glist  = (int*)  (ws + WS_GLIST);
    float* U3sym  = (float*)(ws + WS_U3SYM);
    float* U2sym  = (float*)(ws + WS_U2SYM);
    float* coeff  = (float*)(ws + WS_COEFF);
    float* xg     = (float*)(ws + WS_XG);
    float* fg     = (float*)(ws + WS_FG);
    (void)in_sizes; (void)n_in; (void)out_size; (void)ws_size;

    hipLaunchKernelGGL(k_prep,   dim3(8),    dim3(384), 0, stream,
                       U3_0e, U3_1o, U2_0e, U2_1o, U3sym, U2sym);
    hipLaunchKernelGGL(k_sort,   dim3(1),    dim3(512), 0, stream, spec, cntoff, glist);
    hipLaunchKernelGGL(k_coeff,  dim3(1280), dim3(896), 0, stream,
                       U3sym, U2sym, U1_0e, U1_1o, W3_0e, W3_1o,
                       W2_0e, W2_1o, W1_0e, W1_1o, coeff);
    hipLaunchKernelGGL(k_gather, dim3(1152), dim3(256), 0, stream, x, glist, xg);
    hipLaunchKernelGGL(k_main,   dim3(1280), dim3(256), 0, stream, xg, cntoff, coeff, fg);
    hipLaunchKernelGGL(k_epi,    dim3(512),  dim3(256), 0, stream, fg, Wlin0, Wlin1, bias0, glist, out);
}